// Round 2
// baseline (686.098 us; speedup 1.0000x reference)
//
#include <hip/hip_runtime.h>

// out[i,l] = sum_{j,k} p3[i,j,l] * p5[i,j,k,l] * p3[i,k,l]
// N=100000, J=3, L=128, fp32. Pure streaming: 665.6 MB total traffic,
// ~0.07 FLOP/B -> HBM-bound. float4 vectorized (each thread owns 4 l's).

#define TPL_N 100000
#define TPL_L4 32            // L/4 = 128/4 float4 chunks per (i,j)

__device__ __forceinline__ float4 f4_mul(float4 a, float4 b) {
    return make_float4(a.x * b.x, a.y * b.y, a.z * b.z, a.w * b.w);
}
__device__ __forceinline__ float4 f4_fma(float4 a, float4 b, float4 c) {
    return make_float4(fmaf(a.x, b.x, c.x), fmaf(a.y, b.y, c.y),
                       fmaf(a.z, b.z, c.z), fmaf(a.w, b.w, c.w));
}

__global__ __launch_bounds__(256) void tpl_quadform_kernel(
    const float4* __restrict__ p3,   // [N][3][32] float4
    const float4* __restrict__ p5,   // [N][3][3][32] float4
    float4* __restrict__ out,        // [N][32] float4
    int total)                       // N * 32
{
    int stride = gridDim.x * blockDim.x;
    for (int t = blockIdx.x * blockDim.x + threadIdx.x; t < total; t += stride) {
        int i  = t >> 5;    // atom index
        int l4 = t & 31;    // float4 index within L

        const float4* a_base = p3 + (size_t)i * (3 * TPL_L4) + l4;
        const float4* m_base = p5 + (size_t)i * (9 * TPL_L4) + l4;

        float4 a0 = a_base[0 * TPL_L4];
        float4 a1 = a_base[1 * TPL_L4];
        float4 a2 = a_base[2 * TPL_L4];

        float4 m00 = m_base[0 * TPL_L4];
        float4 m01 = m_base[1 * TPL_L4];
        float4 m02 = m_base[2 * TPL_L4];
        float4 m10 = m_base[3 * TPL_L4];
        float4 m11 = m_base[4 * TPL_L4];
        float4 m12 = m_base[5 * TPL_L4];
        float4 m20 = m_base[6 * TPL_L4];
        float4 m21 = m_base[7 * TPL_L4];
        float4 m22 = m_base[8 * TPL_L4];

        // t_j = sum_k M[j][k] * a[k]
        float4 t0 = f4_fma(m02, a2, f4_fma(m01, a1, f4_mul(m00, a0)));
        float4 t1 = f4_fma(m12, a2, f4_fma(m11, a1, f4_mul(m10, a0)));
        float4 t2 = f4_fma(m22, a2, f4_fma(m21, a1, f4_mul(m20, a0)));

        // out = sum_j a[j] * t_j
        float4 r = f4_fma(a2, t2, f4_fma(a1, t1, f4_mul(a0, t0)));

        out[t] = r;
    }
}

extern "C" void kernel_launch(void* const* d_in, const int* in_sizes, int n_in,
                              void* d_out, int out_size, void* d_ws, size_t ws_size,
                              hipStream_t stream) {
    const float4* p3 = (const float4*)d_in[0];
    const float4* p5 = (const float4*)d_in[1];
    float4* out = (float4*)d_out;

    int total = TPL_N * TPL_L4;              // 3,200,000 threads' worth of work
    int block = 256;
    int grid = (total + block - 1) / block;  // 12500
    if (grid > 2048) grid = 2048;            // grid-stride the rest

    tpl_quadform_kernel<<<grid, block, 0, stream>>>(p3, p5, out, total);
}

// Round 3
// 651.478 us; speedup vs baseline: 1.0531x; 1.0531x over previous
//
#include <hip/hip_runtime.h>

// out[i,l] = sum_{j,k} p3[i,j,l] * p5[i,j,k,l] * p3[i,k,l]
// N=100000, J=3, L=128, fp32. Pure streaming, 665.6 MB total HBM traffic,
// ~0.07 FLOP/B -> HBM-bound. Roofline @6.4 TB/s (fill-measured) ~= 104 us.
//
// R3 changes vs R2: exact-fit grid (12500x256 = N*32 threads, no grid-stride
// loop -> all 12 loads issue back-to-back, no per-iteration vmcnt drain);
// nontemporal ext_vector loads/stores (zero reuse -> skip cache allocate);
// 32-bit index math.

typedef float v4f __attribute__((ext_vector_type(4)));

#define TPL_N 100000

__global__ __launch_bounds__(256) void tpl_quadform_kernel(
    const v4f* __restrict__ p3,   // [N][3][32] v4f
    const v4f* __restrict__ p5,   // [N][3][3][32] v4f
    v4f* __restrict__ out)        // [N][32] v4f
{
    unsigned t  = blockIdx.x * 256u + threadIdx.x;  // exactly N*32 threads
    unsigned i  = t >> 5;                           // atom index
    unsigned l4 = t & 31u;                          // float4 chunk within L

    const v4f* a_base = p3 + i * 96u  + l4;   // 3*32 v4f per atom
    const v4f* m_base = p5 + i * 288u + l4;   // 9*32 v4f per atom

    v4f a0 = __builtin_nontemporal_load(a_base + 0);
    v4f a1 = __builtin_nontemporal_load(a_base + 32);
    v4f a2 = __builtin_nontemporal_load(a_base + 64);

    v4f m00 = __builtin_nontemporal_load(m_base + 0);
    v4f m01 = __builtin_nontemporal_load(m_base + 32);
    v4f m02 = __builtin_nontemporal_load(m_base + 64);
    v4f m10 = __builtin_nontemporal_load(m_base + 96);
    v4f m11 = __builtin_nontemporal_load(m_base + 128);
    v4f m12 = __builtin_nontemporal_load(m_base + 160);
    v4f m20 = __builtin_nontemporal_load(m_base + 192);
    v4f m21 = __builtin_nontemporal_load(m_base + 224);
    v4f m22 = __builtin_nontemporal_load(m_base + 256);

    // t_j = sum_k M[j][k] * a[k]   (elementwise over the 4 packed l's;
    // -ffp-contract fuses to v_fma_f32)
    v4f t0 = m00 * a0 + m01 * a1 + m02 * a2;
    v4f t1 = m10 * a0 + m11 * a1 + m12 * a2;
    v4f t2 = m20 * a0 + m21 * a1 + m22 * a2;

    // out = sum_j a[j] * t_j
    v4f r = a0 * t0 + a1 * t1 + a2 * t2;

    __builtin_nontemporal_store(r, out + t);
}

extern "C" void kernel_launch(void* const* d_in, const int* in_sizes, int n_in,
                              void* d_out, int out_size, void* d_ws, size_t ws_size,
                              hipStream_t stream) {
    const v4f* p3 = (const v4f*)d_in[0];
    const v4f* p5 = (const v4f*)d_in[1];
    v4f* out = (v4f*)d_out;

    int total = TPL_N * 32;                  // 3,200,000 = exactly 12500 blocks
    int block = 256;
    int grid = total / block;                // 12500, exact fit (no tail)

    tpl_quadform_kernel<<<grid, block, 0, stream>>>(p3, p5, out);
}